// Round 14
// baseline (39.383 us; speedup 1.0000x reference)
//
#include <hip/hip_runtime.h>
#include <math.h>

#define NQ 12
#define NN 4096   // 2^12

typedef float f2 __attribute__((ext_vector_type(2)));  // (re, im)
typedef float f4 __attribute__((ext_vector_type(4)));

__device__ __forceinline__ float2 cmulh(float2 a, float2 b) {
    return make_float2(a.x * b.x - a.y * b.y, a.x * b.y + a.y * b.x);
}

// Broadcast (wave-uniform) value -> SGPR pair. Once per kernel, LDS producers.
__device__ __forceinline__ f2 rfl2(f2 a) {
    f2 r;
    r.x = __int_as_float(__builtin_amdgcn_readfirstlane(__float_as_int(a.x)));
    r.y = __int_as_float(__builtin_amdgcn_readfirstlane(__float_as_int(a.y)));
    return r;
}

// ---- packed complex arithmetic: 2 x v_pk_fma_f32 per complex MAC ----
__device__ __forceinline__ void cmac_pk(f2& acc, f2 m, f2 b) {
    asm("v_pk_fma_f32 %0, %1, %2, %0 op_sel:[0,0,0] op_sel_hi:[0,1,1]\n\t"
        "v_pk_fma_f32 %0, %1, %2, %0 op_sel:[1,1,0] op_sel_hi:[1,0,1] neg_lo:[1,0,0]"
        : "+v"(acc) : "s"(m), "v"(b));
}
__device__ __forceinline__ void cmul_pk(f2& r, f2 m, f2 b) {
    asm("v_pk_mul_f32 %0, %1, %2 op_sel:[0,0] op_sel_hi:[0,1]\n\t"
        "v_pk_fma_f32 %0, %1, %2, %0 op_sel:[1,1,0] op_sel_hi:[1,0,1] neg_lo:[1,0,0]"
        : "=&v"(r) : "s"(m), "v"(b));
}

template<int D>
__device__ __forceinline__ void stagepk8(f2 (&v)[8], f2 m00, f2 m01, f2 m10, f2 m11) {
    #pragma unroll
    for (int s = 0; s < 8; ++s) {
        if (s & D) continue;
        f2 va = v[s], vb = v[s | D];
        f2 r0, r1;
        cmul_pk(r0, m00, va); cmac_pk(r0, m01, vb);
        cmul_pk(r1, m10, va); cmac_pk(r1, m11, vb);
        v[s] = r0; v[s | D] = r1;
    }
}

// 3-stage phase (3 bits) with matrices Mp[0..11].
__device__ __forceinline__ void phase3(f2 (&v)[8], const f2* Mp) {
    stagepk8<1>(v, Mp[0], Mp[1], Mp[2],  Mp[3]);
    stagepk8<2>(v, Mp[4], Mp[5], Mp[6],  Mp[7]);
    stagepk8<4>(v, Mp[8], Mp[9], Mp[10], Mp[11]);
}

// ---- transpose pieces (LDS idx(i) = i + (i>>3); see mapping table below) ----
__device__ __forceinline__ void t1w(f2* lds, int T, f2 (&v)[8]) {      // A-write
    f2* wp = lds + 9 * T;
    #pragma unroll
    for (int s = 0; s < 8; ++s) wp[s] = v[s];
}
__device__ __forceinline__ void t1r(f2* lds, int T, f2 (&v)[8]) {      // B-read
    const f2* rp = lds + 72 * (T >> 3) + (T & 7);
    #pragma unroll
    for (int s = 0; s < 8; ++s) v[s] = rp[9 * s];
}
__device__ __forceinline__ void t2w(f2* lds, int T, f2 (&v)[8]) {      // B-write
    f2* wp = lds + 72 * (T >> 3) + (T & 7);
    #pragma unroll
    for (int s = 0; s < 8; ++s) wp[9 * s] = v[s];
}
__device__ __forceinline__ void t2r(f2* lds, int T, f2 (&v)[8]) {      // C-read
    const f2* rp = lds + 576 * (T >> 6) + (T & 63) + ((T & 63) >> 3);
    #pragma unroll
    for (int s = 0; s < 8; ++s) v[s] = rp[72 * s];
}
__device__ __forceinline__ void t3w(f2* lds, int T, f2 (&v)[8]) {      // C-write
    f2* wp = lds + 576 * (T >> 6) + (T & 63) + ((T & 63) >> 3);
    #pragma unroll
    for (int s = 0; s < 8; ++s) wp[72 * s] = v[s];
}
__device__ __forceinline__ void dread(f2* lds, int T, f2 (&v)[8]) {    // D-read (cross-wave)
    const f2* rp = lds + T + (T >> 3);   // idx(s<<9 | T) = 576s + T + (T>>3)
    #pragma unroll
    for (int s = 0; s < 8; ++s) v[s] = rp[576 * s];
}
__device__ __forceinline__ void storeD(float* po, int T, f2 (&v)[8]) { // NT store
    #pragma unroll
    for (int s = 0; s < 8; ++s) {
        int i = (s << 9) | T;
        __builtin_nontemporal_store(v[s].x, po + i);
        __builtin_nontemporal_store(v[s].y, po + NN + i);
    }
}

// Single kernel. 512 threads/block, TWO rows per block (grid = 1024, fully
// resident at 4 blocks/CU = 32 waves/CU), 8 complex elements/thread.
// DUAL-ROW SOFTWARE PIPELINE: the two rows are data-independent; their
// phases are interleaved in one basic block so row-1 VALU fills row-0 DS
// latency and vice versa (R12's serial r-loop left VALU 24% / DS / HBM all
// unsaturated — the phase convoy). LDS hazards are ordered by the same-wave
// in-order DS pipe (all sets wave-region-local): T1w(v1)[A] after T2r(v0)[C],
// T3w(v0)[C] after T1r(v1)[B], T2w(v1)[B] after barrier b2. Same 4 barriers
// as R12 (Msh + b1/b2/b3).
// Mappings (T = thread 9 bits, s = slot 3 bits):
//   A: i = T<<3 | s; B: i = (T>>3)<<6 | s<<3 | (T&7);
//   C: i = (T>>6)<<9 | s<<6 | (T&63); D: i = s<<9 | T.
// idx(i) = i + (i>>3) padding; residual SQ_LDS_BANK_CONFLICT = 1 cyc per
// wave-b64 op (b64 floor, verified exact in R10). NT stores (never re-read).
__global__ __launch_bounds__(512, 8) void sq_layer(const float* __restrict__ x,
                                                   float* __restrict__ out,
                                                   const float* __restrict__ alphas,
                                                   const float* __restrict__ betas,
                                                   const float* __restrict__ thetas,
                                                   const float* __restrict__ phis) {
    __shared__ f2 lds[4608];              // 36 KB
    __shared__ __align__(16) f2 Msh[48];  // +384 B
    const int T = threadIdx.x;
    const size_t row0 = (size_t)blockIdx.x * 2;

    // ---- issue ALL global loads (both rows) first ----
    const float* px = x + row0 * (2 * NN) + (T << 3);
    float4 ra0 = *reinterpret_cast<const float4*>(px);
    float4 rb0 = *reinterpret_cast<const float4*>(px + 4);
    float4 ia0 = *reinterpret_cast<const float4*>(px + NN);
    float4 ib0 = *reinterpret_cast<const float4*>(px + NN + 4);
    float4 ra1 = *reinterpret_cast<const float4*>(px + 2 * NN);
    float4 rb1 = *reinterpret_cast<const float4*>(px + 2 * NN + 4);
    float4 ia1 = *reinterpret_cast<const float4*>(px + 3 * NN);
    float4 ib1 = *reinterpret_cast<const float4*>(px + 3 * NN + 4);

    // ---- per-block matrix setup (hides under the load burst) ----
    if (T < NQ) {
        int p = T, q = NQ - 1 - p;
        float av = alphas[q], bv = betas[q], tv = thetas[q], fv = phis[q];
        float sa = __sinf(av), ca = __cosf(av);
        float sb = __sinf(bv), cb = __cosf(bv);
        float st = __sinf(tv), ct = __cosf(tv);
        float sf = __sinf(fv), cf = __cosf(fv);
        float2 A  = make_float2(ca, sa);
        float2 Bb = make_float2(cb, sb);
        float2 F  = make_float2(cf, sf);
        float2 Tm  = make_float2(0.5f * (ct - 1.0f), 0.5f * st);  // (T-1)/2
        float2 Tp  = make_float2(0.5f * (ct + 1.0f), 0.5f * st);  // (T+1)/2
        float2 iTp = make_float2(-Tp.y, Tp.x);                    // i*(T+1)/2
        float2 m00 = cmulh(cmulh(F, Tm), A);
        float2 m01 = cmulh(cmulh(F, iTp), Bb);
        float2 m10 = cmulh(iTp, A);
        float2 m11 = cmulh(make_float2(-Tm.x, -Tm.y), Bb);
        Msh[p * 4 + 0] = f2{m00.x, m00.y};
        Msh[p * 4 + 1] = f2{m01.x, m01.y};
        Msh[p * 4 + 2] = f2{m10.x, m10.y};
        Msh[p * 4 + 3] = f2{m11.x, m11.y};
    }
    __syncthreads();  // Msh visible

    // ---- pin all 48 matrix values to SGPRs (once per kernel) ----
    f2 M[48];
    #pragma unroll
    for (int k = 0; k < 24; ++k) {
        f4 two = *reinterpret_cast<const f4*>(&Msh[k * 2]);  // ds_read_b128
        M[k * 2 + 0] = rfl2(f2{two.x, two.y});
        M[k * 2 + 1] = rfl2(f2{two.z, two.w});
    }

    // ---- dual-row pipeline ----
    f2 v0[8], v1[8];
    v0[0] = f2{ra0.x, ia0.x}; v0[1] = f2{ra0.y, ia0.y};
    v0[2] = f2{ra0.z, ia0.z}; v0[3] = f2{ra0.w, ia0.w};
    v0[4] = f2{rb0.x, ib0.x}; v0[5] = f2{rb0.y, ib0.y};
    v0[6] = f2{rb0.z, ib0.z}; v0[7] = f2{rb0.w, ib0.w};

    phase3(v0, M + 0);                 // P1(v0)
    t1w(lds, T, v0); t1r(lds, T, v0);  // T1(v0)

    v1[0] = f2{ra1.x, ia1.x}; v1[1] = f2{ra1.y, ia1.y};
    v1[2] = f2{ra1.z, ia1.z}; v1[3] = f2{ra1.w, ia1.w};
    v1[4] = f2{rb1.x, ib1.x}; v1[5] = f2{rb1.y, ib1.y};
    v1[6] = f2{rb1.z, ib1.z}; v1[7] = f2{rb1.w, ib1.w};
    phase3(v1, M + 0);                 // P1(v1) — fills T1r(v0) latency

    phase3(v0, M + 12);                // P2(v0)
    t2w(lds, T, v0); t2r(lds, T, v0);  // T2(v0)
    t1w(lds, T, v1); t1r(lds, T, v1);  // T1(v1): A-writes AFTER T2r(v0) C-reads (in-order pipe)

    phase3(v0, M + 24);                // P3(v0) — runs during T1(v1) DS
    phase3(v1, M + 12);                // P2(v1)

    t3w(lds, T, v0);                   // C-write AFTER T1r(v1) consumed its data
    __syncthreads();                   // b1: all C-writes of v0 visible
    dread(lds, T, v0);                 // D-read (cross-wave)
    phase3(v0, M + 36);                // P4(v0)
    storeD(out + row0 * (2 * NN), T, v0);  // start the write stream early
    __syncthreads();                   // b2: all waves' D-reads of v0 done

    t2w(lds, T, v1); t2r(lds, T, v1);  // T2(v1) — buffer free after b2
    phase3(v1, M + 24);                // P3(v1)
    t3w(lds, T, v1);
    __syncthreads();                   // b3
    dread(lds, T, v1);
    phase3(v1, M + 36);                // P4(v1)
    storeD(out + (row0 + 1) * (2 * NN), T, v1);
}

extern "C" void kernel_launch(void* const* d_in, const int* in_sizes, int n_in,
                              void* d_out, int out_size, void* d_ws, size_t ws_size,
                              hipStream_t stream) {
    const float* x      = (const float*)d_in[0];
    const float* alphas = (const float*)d_in[1];
    const float* betas  = (const float*)d_in[2];
    const float* thetas = (const float*)d_in[3];
    const float* phis   = (const float*)d_in[4];
    float* out = (float*)d_out;

    const int B = in_sizes[0] / (2 * NN);  // 2048

    hipLaunchKernelGGL(sq_layer, dim3(B / 2), dim3(512), 0, stream,
                       x, out, alphas, betas, thetas, phis);
}

// Round 15
// 28.408 us; speedup vs baseline: 1.3863x; 1.3863x over previous
//
#include <hip/hip_runtime.h>
#include <math.h>

#define NQ 12
#define NN 4096   // 2^12

typedef float f2 __attribute__((ext_vector_type(2)));  // (re, im)
typedef float f4 __attribute__((ext_vector_type(4)));

__device__ __forceinline__ float2 cmulh(float2 a, float2 b) {
    return make_float2(a.x * b.x - a.y * b.y, a.x * b.y + a.y * b.x);
}

// Broadcast (wave-uniform) value -> SGPR pair. Used ONCE per kernel on LDS
// reads — cheap producers, unlike R8's trig chains that strangled the
// allocator. R2/R3/R6 prove SGPR_Count=112 (96 matrix SGPRs) allocates fine.
__device__ __forceinline__ f2 rfl2(f2 a) {
    f2 r;
    r.x = __int_as_float(__builtin_amdgcn_readfirstlane(__float_as_int(a.x)));
    r.y = __int_as_float(__builtin_amdgcn_readfirstlane(__float_as_int(a.y)));
    return r;
}

// ---- packed complex arithmetic: 2 x v_pk_fma_f32 per complex MAC ----
// m = [mr, mi] (SGPR pair, uniform), b = [br, bi], acc = [ar, ai].
__device__ __forceinline__ void cmac_pk(f2& acc, f2 m, f2 b) {
    asm("v_pk_fma_f32 %0, %1, %2, %0 op_sel:[0,0,0] op_sel_hi:[0,1,1]\n\t"
        "v_pk_fma_f32 %0, %1, %2, %0 op_sel:[1,1,0] op_sel_hi:[1,0,1] neg_lo:[1,0,0]"
        : "+v"(acc) : "s"(m), "v"(b));
}
__device__ __forceinline__ void cmul_pk(f2& r, f2 m, f2 b) {
    asm("v_pk_mul_f32 %0, %1, %2 op_sel:[0,0] op_sel_hi:[0,1]\n\t"
        "v_pk_fma_f32 %0, %1, %2, %0 op_sel:[1,1,0] op_sel_hi:[1,0,1] neg_lo:[1,0,0]"
        : "=&v"(r) : "s"(m), "v"(b));
}

// Radix-2 butterfly on slot bit log2(D) over 8 slots.
template<int D>
__device__ __forceinline__ void stagepk8(f2 (&v)[8], f2 m00, f2 m01, f2 m10, f2 m11) {
    #pragma unroll
    for (int s = 0; s < 8; ++s) {
        if (s & D) continue;
        f2 va = v[s], vb = v[s | D];
        f2 r0, r1;
        cmul_pk(r0, m00, va); cmac_pk(r0, m01, vb);
        cmul_pk(r1, m10, va); cmac_pk(r1, m11, vb);
        v[s] = r0; v[s | D] = r1;
    }
}

// Single kernel. 512 threads/block, TWO batch rows per block (grid = B/2 =
// 1024, fully resident at 4 blocks/CU = the 32-wave/CU HW cap), 8 complex
// elements/thread. Threads 0..11 compute the 12 per-bit matrices into Msh
// (fast trig, hidden under the global-load burst); after one barrier, ALL 48
// complex values are pinned to SGPRs via 24 ds_read_b128 + 96 readfirstlane.
// M_p = diag(e^{i phi},1) * u * diag(e^{i theta},1) * u * diag(e^{i a}, e^{i b}),
// u = (1/sqrt2)[[1,i],[i,1]], parameter index q = 11-p.
//
// Mappings (T = thread 9 bits, s = slot 3 bits):
//   A: i = T<<3 | s                         -> slot bits {0,1,2}
//   B: i = (T>>3)<<6 | s<<3 | (T&7)         -> slot bits {3,4,5}
//   C: i = (T>>6)<<9 | s<<6 | (T&63)        -> slot bits {6,7,8}
//   D: i = s<<9 | T                         -> slot bits {9,10,11}
// LDS layout: idx(i) = i + (i>>3) (stride-9/8 padding; 4608 f2 = 36 KB).
// Transposes A->B, B->C and the C-write of C->D are wave-region-local
// (i[11:9]==T[8:6]; in-order DS pipe, no barrier). Only the D-read crosses
// waves -> barrier before it + one after (row 0 only). Residual
// SQ_LDS_BANK_CONFLICT = 1 cyc per wave-b64 op (verified exact in R10) is
// the b64 floor. Stores non-temporal (output never re-read).
//
// Structural ledger (R3-R14): prefetch depth null (R10), occupancy/row
// trades negative (R3/R13), dual-row manual pipeline spills at the 64-VGPR
// cap (R14, FETCH +15MB scratch). This shape is the measured optimum.
__global__ __launch_bounds__(512, 8) void sq_layer(const float* __restrict__ x,
                                                   float* __restrict__ out,
                                                   const float* __restrict__ alphas,
                                                   const float* __restrict__ betas,
                                                   const float* __restrict__ thetas,
                                                   const float* __restrict__ phis) {
    __shared__ f2 lds[4608];              // 36 KB
    __shared__ __align__(16) f2 Msh[48];  // +384 B
    const int T = threadIdx.x;
    const size_t row0 = (size_t)blockIdx.x * 2;

    // ---- issue ALL global loads (both rows) first ----
    const float* px = x + row0 * (2 * NN) + (T << 3);
    float4 ra0 = *reinterpret_cast<const float4*>(px);
    float4 rb0 = *reinterpret_cast<const float4*>(px + 4);
    float4 ia0 = *reinterpret_cast<const float4*>(px + NN);
    float4 ib0 = *reinterpret_cast<const float4*>(px + NN + 4);
    float4 ra1 = *reinterpret_cast<const float4*>(px + 2 * NN);
    float4 rb1 = *reinterpret_cast<const float4*>(px + 2 * NN + 4);
    float4 ia1 = *reinterpret_cast<const float4*>(px + 3 * NN);
    float4 ib1 = *reinterpret_cast<const float4*>(px + 3 * NN + 4);

    // ---- per-block matrix setup (hides under the load burst) ----
    if (T < NQ) {
        int p = T, q = NQ - 1 - p;
        float av = alphas[q], bv = betas[q], tv = thetas[q], fv = phis[q];
        float sa = __sinf(av), ca = __cosf(av);
        float sb = __sinf(bv), cb = __cosf(bv);
        float st = __sinf(tv), ct = __cosf(tv);
        float sf = __sinf(fv), cf = __cosf(fv);
        float2 A  = make_float2(ca, sa);
        float2 Bb = make_float2(cb, sb);
        float2 F  = make_float2(cf, sf);
        float2 Tm  = make_float2(0.5f * (ct - 1.0f), 0.5f * st);  // (T-1)/2
        float2 Tp  = make_float2(0.5f * (ct + 1.0f), 0.5f * st);  // (T+1)/2
        float2 iTp = make_float2(-Tp.y, Tp.x);                    // i*(T+1)/2
        float2 m00 = cmulh(cmulh(F, Tm), A);
        float2 m01 = cmulh(cmulh(F, iTp), Bb);
        float2 m10 = cmulh(iTp, A);
        float2 m11 = cmulh(make_float2(-Tm.x, -Tm.y), Bb);
        Msh[p * 4 + 0] = f2{m00.x, m00.y};
        Msh[p * 4 + 1] = f2{m01.x, m01.y};
        Msh[p * 4 + 2] = f2{m10.x, m10.y};
        Msh[p * 4 + 3] = f2{m11.x, m11.y};
    }
    __syncthreads();  // Msh visible to all waves

    // ---- pin all 48 matrix values to SGPRs (once per kernel) ----
    f2 M[48];
    #pragma unroll
    for (int k = 0; k < 24; ++k) {
        f4 two = *reinterpret_cast<const f4*>(&Msh[k * 2]);  // ds_read_b128
        M[k * 2 + 0] = rfl2(f2{two.x, two.y});
        M[k * 2 + 1] = rfl2(f2{two.z, two.w});
    }

    #pragma unroll
    for (int r = 0; r < 2; ++r) {
        f2 v[8];
        if (r == 0) {
            v[0] = f2{ra0.x, ia0.x}; v[1] = f2{ra0.y, ia0.y};
            v[2] = f2{ra0.z, ia0.z}; v[3] = f2{ra0.w, ia0.w};
            v[4] = f2{rb0.x, ib0.x}; v[5] = f2{rb0.y, ib0.y};
            v[6] = f2{rb0.z, ib0.z}; v[7] = f2{rb0.w, ib0.w};
        } else {
            v[0] = f2{ra1.x, ia1.x}; v[1] = f2{ra1.y, ia1.y};
            v[2] = f2{ra1.z, ia1.z}; v[3] = f2{ra1.w, ia1.w};
            v[4] = f2{rb1.x, ib1.x}; v[5] = f2{rb1.y, ib1.y};
            v[6] = f2{rb1.z, ib1.z}; v[7] = f2{rb1.w, ib1.w};
        }

        // ---- phase 1: bits 0,1,2 ----
        stagepk8<1>(v, M[0],  M[1],  M[2],  M[3]);
        stagepk8<2>(v, M[4],  M[5],  M[6],  M[7]);
        stagepk8<4>(v, M[8],  M[9],  M[10], M[11]);

        // ---- transpose A -> B (wave-region-local, no barrier) ----
        {
            f2* wp = lds + 9 * T;
            #pragma unroll
            for (int s = 0; s < 8; ++s) wp[s] = v[s];
        }
        {
            const f2* rp = lds + 72 * (T >> 3) + (T & 7);
            #pragma unroll
            for (int s = 0; s < 8; ++s) v[s] = rp[9 * s];
        }

        // ---- phase 2: bits 3,4,5 ----
        stagepk8<1>(v, M[12], M[13], M[14], M[15]);
        stagepk8<2>(v, M[16], M[17], M[18], M[19]);
        stagepk8<4>(v, M[20], M[21], M[22], M[23]);

        // ---- transpose B -> C (wave-region-local, no barrier) ----
        {
            f2* wp = lds + 72 * (T >> 3) + (T & 7);
            #pragma unroll
            for (int s = 0; s < 8; ++s) wp[9 * s] = v[s];
        }
        {
            const f2* rp = lds + 576 * (T >> 6) + (T & 63) + ((T & 63) >> 3);
            #pragma unroll
            for (int s = 0; s < 8; ++s) v[s] = rp[72 * s];
        }

        // ---- phase 3: bits 6,7,8 ----
        stagepk8<1>(v, M[24], M[25], M[26], M[27]);
        stagepk8<2>(v, M[28], M[29], M[30], M[31]);
        stagepk8<4>(v, M[32], M[33], M[34], M[35]);

        // ---- transpose C -> D: write C (own region), BARRIER, read D ----
        {
            f2* wp = lds + 576 * (T >> 6) + (T & 63) + ((T & 63) >> 3);
            #pragma unroll
            for (int s = 0; s < 8; ++s) wp[72 * s] = v[s];
        }
        __syncthreads();
        {
            const f2* rp = lds + T + (T >> 3);   // idx(s<<9 | T) = 576s + T + (T>>3)
            #pragma unroll
            for (int s = 0; s < 8; ++s) v[s] = rp[576 * s];
        }
        if (r == 0) __syncthreads();  // D-reads done before row 1's A-writes

        // ---- phase 4: bits 9,10,11 ----
        stagepk8<1>(v, M[36], M[37], M[38], M[39]);
        stagepk8<2>(v, M[40], M[41], M[42], M[43]);
        stagepk8<4>(v, M[44], M[45], M[46], M[47]);

        // ---- store (mapping D): i = s<<9 | T, wave-contiguous, non-temporal ----
        {
            float* po = out + (row0 + r) * (2 * NN);
            #pragma unroll
            for (int s = 0; s < 8; ++s) {
                int i = (s << 9) | T;
                __builtin_nontemporal_store(v[s].x, po + i);
                __builtin_nontemporal_store(v[s].y, po + NN + i);
            }
        }
    }
}

extern "C" void kernel_launch(void* const* d_in, const int* in_sizes, int n_in,
                              void* d_out, int out_size, void* d_ws, size_t ws_size,
                              hipStream_t stream) {
    const float* x      = (const float*)d_in[0];
    const float* alphas = (const float*)d_in[1];
    const float* betas  = (const float*)d_in[2];
    const float* thetas = (const float*)d_in[3];
    const float* phis   = (const float*)d_in[4];
    float* out = (float*)d_out;

    const int B = in_sizes[0] / (2 * NN);  // 2048

    hipLaunchKernelGGL(sq_layer, dim3(B / 2), dim3(512), 0, stream,
                       x, out, alphas, betas, thetas, phis);
}